// Round 1
// baseline (1264.288 us; speedup 1.0000x reference)
//
#include <hip/hip_runtime.h>

typedef __attribute__((ext_vector_type(8))) __bf16 bf16x8;
typedef __attribute__((ext_vector_type(4))) float f32x4;

#define DMODEL 1024
#define SEQ 1024
#define NLAYER 4

__device__ __forceinline__ unsigned short f2bf(float f) {
  unsigned u = __float_as_uint(f);
  u += 0x7fffu + ((u >> 16) & 1u);
  return (unsigned short)(u >> 16);
}

__device__ __forceinline__ void async_copy16(const void* gsrc, const void* lds_dst) {
  __builtin_amdgcn_global_load_lds(
      (__attribute__((address_space(1))) void*)(unsigned long long)(gsrc),
      (__attribute__((address_space(3))) void*)(unsigned int)(unsigned long long)(lds_dst),
      16, 0, 0);
}

__device__ __forceinline__ f32x4 mfma16(bf16x8 a, bf16x8 b, f32x4 c) {
  return __builtin_amdgcn_mfma_f32_16x16x32_bf16(a, b, c, 0, 0, 0);
}

// ---------------- embedding + positional encoding ----------------
__global__ __launch_bounds__(256) void embed_kernel(
    const int* __restrict__ tok, const float* __restrict__ emb,
    float* __restrict__ xf, unsigned short* __restrict__ xb) {
  const int row = blockIdx.x;          // b*T + t
  const int t = row & (SEQ - 1);
  const int tk = tok[row];
  const int col = threadIdx.x * 4;
  float4 e = *(const float4*)(emb + (size_t)tk * DMODEL + col);
  const float c = -9.21034037197618f / (float)DMODEL;  // -ln(10000)/D
  float d0 = __expf((float)(col)*c);
  float d1 = __expf((float)(col + 2) * c);
  float a0 = (float)t * d0, a1 = (float)t * d1;
  e.x += sinf(a0); e.y += cosf(a0); e.z += sinf(a1); e.w += cosf(a1);
  *(float4*)(xf + (size_t)row * DMODEL + col) = e;
  ushort4 ub;
  ub.x = f2bf(e.x); ub.y = f2bf(e.y); ub.z = f2bf(e.z); ub.w = f2bf(e.w);
  *(ushort4*)(xb + (size_t)row * DMODEL + col) = ub;
}

// ---------------- transpose + f32->bf16 convert: dst[N][K] = src[K][N] ----------------
__global__ __launch_bounds__(256) void trconv_kernel(
    const float* __restrict__ src, unsigned short* __restrict__ dst,
    int R, int C, long sls, long dls) {
  src += (size_t)blockIdx.z * sls;
  dst += (size_t)blockIdx.z * dls;
  __shared__ float tile[32][33];
  const int c0 = blockIdx.x * 32, r0 = blockIdx.y * 32;
  const int tx = threadIdx.x, ty = threadIdx.y;
#pragma unroll
  for (int j = 0; j < 4; ++j)
    tile[ty + j * 8][tx] = src[(size_t)(r0 + ty + j * 8) * C + c0 + tx];
  __syncthreads();
#pragma unroll
  for (int j = 0; j < 4; ++j) {
    int rr = ty + j * 8;
    dst[(size_t)(c0 + rr) * R + r0 + tx] = f2bf(tile[tx][rr]);
  }
}

// ---------------- concat q/k/v biases ----------------
__global__ __launch_bounds__(256) void qkvb_kernel(
    const float* __restrict__ bq, const float* __restrict__ bk,
    const float* __restrict__ bv, float* __restrict__ qb) {
  int i = blockIdx.x * 256 + threadIdx.x;
  if (i >= NLAYER * 3072) return;
  int l = i / 3072, j = i % 3072;
  float v = (j < 1024) ? bq[l * 1024 + j]
          : (j < 2048) ? bk[l * 1024 + j - 1024]
                       : bv[l * 1024 + j - 2048];
  qb[i] = v;
}

// ---------------- bf16 GEMM: C[M,N] = A[M,K] @ Bt[N,K]^T + bias ----------------
// m97 structure: 128x128 tile, BK=32, 4 waves (2x2), global_load_lds, dbuf LDS.
template <int RELU, int OUTF, int OUTB>
__global__ __launch_bounds__(256, 2) void gemm_bf16(
    const unsigned short* __restrict__ A, const unsigned short* __restrict__ Bt,
    const float* __restrict__ bias, float* __restrict__ Cf,
    unsigned short* __restrict__ Cb, int M, int N, int K, int qcut) {
  __shared__ unsigned short As[2][128 * 32];
  __shared__ unsigned short Bs[2][128 * 32];
  const int tid = threadIdx.x;
  const int wv = tid >> 6, lane = tid & 63, lr = lane & 15, g = lane >> 4;
  const int wr = wv >> 1, wc = wv & 1;
  const int rm = blockIdx.y * 128, rn = blockIdx.x * 128;
  const int nk = K >> 5;

  auto stage = [&](int buf, int kt) {
#pragma unroll
    for (int q = 0; q < 2; ++q) {
      int c = q * 256 + tid;
      const unsigned short* ga = A + (size_t)(rm + (c >> 2)) * K + (kt << 5) + (c & 3) * 8;
      async_copy16(ga, &As[buf][q * 2048 + wv * 512]);
      const unsigned short* gb = Bt + (size_t)(rn + (c >> 2)) * K + (kt << 5) + (c & 3) * 8;
      async_copy16(gb, &Bs[buf][q * 2048 + wv * 512]);
    }
  };

  f32x4 acc[4][4] = {};
  stage(0, 0);
  for (int kt = 0; kt < nk; ++kt) {
    __syncthreads();
    if (kt + 1 < nk) stage((kt + 1) & 1, kt + 1);
    const int cur = kt & 1;
    const unsigned short* pa = &As[cur][(wr * 64 + lr) * 32 + g * 8];
    const unsigned short* pb = &Bs[cur][(wc * 64 + lr) * 32 + g * 8];
    bf16x8 af[4], bfr[4];
#pragma unroll
    for (int i = 0; i < 4; ++i) {
      af[i] = *(const bf16x8*)(pa + i * 512);
      bfr[i] = *(const bf16x8*)(pb + i * 512);
    }
#pragma unroll
    for (int mi = 0; mi < 4; ++mi)
#pragma unroll
      for (int ni = 0; ni < 4; ++ni)
        acc[mi][ni] = mfma16(af[mi], bfr[ni], acc[mi][ni]);
  }
  const int row0 = rm + wr * 64 + g * 4;
  const int col0 = rn + wc * 64 + lr;
#pragma unroll
  for (int ni = 0; ni < 4; ++ni) {
    int col = col0 + ni * 16;
    float bv = bias[col];
    float sc = (col < qcut) ? 0.125f : 1.0f;
#pragma unroll
    for (int mi = 0; mi < 4; ++mi) {
#pragma unroll
      for (int r = 0; r < 4; ++r) {
        int row = row0 + mi * 16 + r;
        float v = (acc[mi][ni][r] + bv) * sc;
        if (RELU) v = fmaxf(v, 0.0f);
        if (OUTF) Cf[(size_t)row * N + col] = v;
        if (OUTB) Cb[(size_t)row * N + col] = f2bf(v);
      }
    }
  }
}

// ---------------- fused causal attention ----------------
// qkv: [4096][3072] bf16 (q|k|v, q pre-scaled by 1/8). out: [4096][1024] bf16.
// One block = 64 q-rows of one (b,h); 4 waves x 16 rows; 32-key tiles.
__global__ __launch_bounds__(256, 2) void attn_kernel(
    const unsigned short* __restrict__ qkv, unsigned short* __restrict__ out) {
  __shared__ unsigned short Vl[2][32 * 64];
  __shared__ unsigned short Pl[4][16 * 40];
  const int tid = threadIdx.x;
  const int w = tid >> 6, lane = tid & 63, lr = lane & 15, g = lane >> 4;
  const int qblk = blockIdx.x, bh = blockIdx.y;
  const int b = bh >> 4, h = bh & 15;
  const int qb0 = qblk * 64 + w * 16;
  const size_t rowBase = (size_t)b * SEQ;
  const int cq = h * 64, ck = 1024 + h * 64, cv = 2048 + h * 64;

  bf16x8 aq[2];
#pragma unroll
  for (int ks = 0; ks < 2; ++ks)
    aq[ks] = *(const bf16x8*)(qkv + (rowBase + qb0 + lr) * 3072 + cq + ks * 32 + g * 8);

  f32x4 o[4] = {};
  float m_[4], l_[4];
#pragma unroll
  for (int r = 0; r < 4; ++r) { m_[r] = -1e30f; l_[r] = 0.0f; }

  const int NT = qblk * 2 + 2;
  auto stageV = [&](int buf, int kt) {
    int key = tid >> 3, d8 = (tid & 7) * 8;
    const unsigned short* gv = qkv + (rowBase + kt * 32 + key) * 3072 + cv + d8;
    async_copy16(gv, &Vl[buf][w * 512]);
  };
  stageV(0, 0);
  for (int kt = 0; kt < NT; ++kt) {
    __syncthreads();
    if (kt + 1 < NT) stageV((kt + 1) & 1, kt + 1);
    if (kt * 32 <= qb0 + 15) {
      const int cur = kt & 1;
      f32x4 s0 = {}, s1 = {};
      {
        const unsigned short* kb = qkv + (rowBase + kt * 32) * 3072 + ck;
        bf16x8 k00 = *(const bf16x8*)(kb + (size_t)(lr)*3072 + g * 8);
        bf16x8 k01 = *(const bf16x8*)(kb + (size_t)(lr)*3072 + 32 + g * 8);
        bf16x8 k10 = *(const bf16x8*)(kb + (size_t)(16 + lr) * 3072 + g * 8);
        bf16x8 k11 = *(const bf16x8*)(kb + (size_t)(16 + lr) * 3072 + 32 + g * 8);
        s0 = mfma16(aq[0], k00, s0);
        s0 = mfma16(aq[1], k01, s0);
        s1 = mfma16(aq[0], k10, s1);
        s1 = mfma16(aq[1], k11, s1);
      }
      const int key0 = kt * 32 + lr, key1 = kt * 32 + 16 + lr;
      float p0[4], p1[4];
#pragma unroll
      for (int r = 0; r < 4; ++r) {
        int q = qb0 + g * 4 + r;
        float v0 = (key0 <= q) ? s0[r] : -1e30f;
        float v1 = (key1 <= q) ? s1[r] : -1e30f;
        float mx = fmaxf(v0, v1);
        mx = fmaxf(mx, __shfl_xor(mx, 1, 64));
        mx = fmaxf(mx, __shfl_xor(mx, 2, 64));
        mx = fmaxf(mx, __shfl_xor(mx, 4, 64));
        mx = fmaxf(mx, __shfl_xor(mx, 8, 64));
        float mn = fmaxf(m_[r], mx);
        float sc = __expf(m_[r] - mn);
        float e0 = __expf(v0 - mn), e1 = __expf(v1 - mn);
        p0[r] = e0; p1[r] = e1;
        float rs = e0 + e1;
        rs += __shfl_xor(rs, 1, 64);
        rs += __shfl_xor(rs, 2, 64);
        rs += __shfl_xor(rs, 4, 64);
        rs += __shfl_xor(rs, 8, 64);
        l_[r] = l_[r] * sc + rs;
        m_[r] = mn;
        o[0][r] *= sc; o[1][r] *= sc; o[2][r] *= sc; o[3][r] *= sc;
      }
#pragma unroll
      for (int r = 0; r < 4; ++r) {
        Pl[w][(g * 4 + r) * 40 + lr] = f2bf(p0[r]);
        Pl[w][(g * 4 + r) * 40 + 16 + lr] = f2bf(p1[r]);
      }
      asm volatile("s_waitcnt lgkmcnt(0)" ::: "memory");
      bf16x8 pa = *(const bf16x8*)&Pl[w][lr * 40 + g * 8];
#pragma unroll
      for (int nbv = 0; nbv < 4; ++nbv) {
        union { bf16x8 v; unsigned short u[8]; } vf;
#pragma unroll
        for (int i = 0; i < 8; ++i)
          vf.u[i] = Vl[cur][(g * 8 + i) * 64 + nbv * 16 + lr];
        o[nbv] = mfma16(pa, vf.v, o[nbv]);
      }
    }
  }
#pragma unroll
  for (int nbv = 0; nbv < 4; ++nbv)
#pragma unroll
    for (int r = 0; r < 4; ++r) {
      float val = o[nbv][r] / l_[r];
      out[(rowBase + qb0 + g * 4 + r) * 1024 + h * 64 + nbv * 16 + lr] = f2bf(val);
    }
}

// ---------------- residual add + layernorm ----------------
__global__ __launch_bounds__(256) void ln_kernel(
    const float* __restrict__ xin, const float* __restrict__ yin,
    const float* __restrict__ gam, const float* __restrict__ bet,
    float* __restrict__ xout, unsigned short* __restrict__ xbf,
    float* __restrict__ out2) {
  const int row = blockIdx.x;
  const int col = threadIdx.x * 4;
  const int lane = threadIdx.x & 63, w = threadIdx.x >> 6;
  float4 xv = *(const float4*)(xin + (size_t)row * DMODEL + col);
  float4 yv = *(const float4*)(yin + (size_t)row * DMODEL + col);
  float4 v = {xv.x + yv.x, xv.y + yv.y, xv.z + yv.z, xv.w + yv.w};
  float s = v.x + v.y + v.z + v.w;
  float ss = v.x * v.x + v.y * v.y + v.z * v.z + v.w * v.w;
#pragma unroll
  for (int msk = 32; msk; msk >>= 1) {
    s += __shfl_xor(s, msk, 64);
    ss += __shfl_xor(ss, msk, 64);
  }
  __shared__ float ps[4], pss[4];
  if (lane == 0) { ps[w] = s; pss[w] = ss; }
  __syncthreads();
  float tot = ps[0] + ps[1] + ps[2] + ps[3];
  float tots = pss[0] + pss[1] + pss[2] + pss[3];
  float mean = tot * (1.0f / DMODEL);
  float var = tots * (1.0f / DMODEL) - mean * mean;
  float inv = rsqrtf(var + 1e-5f);
  float4 gv = *(const float4*)(gam + col);
  float4 bv = *(const float4*)(bet + col);
  float4 ov;
  ov.x = (v.x - mean) * inv * gv.x + bv.x;
  ov.y = (v.y - mean) * inv * gv.y + bv.y;
  ov.z = (v.z - mean) * inv * gv.z + bv.z;
  ov.w = (v.w - mean) * inv * gv.w + bv.w;
  *(float4*)(xout + (size_t)row * DMODEL + col) = ov;
  ushort4 ub;
  ub.x = f2bf(ov.x); ub.y = f2bf(ov.y); ub.z = f2bf(ov.z); ub.w = f2bf(ov.w);
  *(ushort4*)(xbf + (size_t)row * DMODEL + col) = ub;
  if (out2) *(float4*)(out2 + (size_t)row * DMODEL + col) = ov;
}

extern "C" void kernel_launch(void* const* d_in, const int* in_sizes, int n_in,
                              void* d_out, int out_size, void* d_ws, size_t ws_size,
                              hipStream_t stream) {
  (void)in_sizes; (void)n_in; (void)out_size; (void)ws_size;
  const int* tok = (const int*)d_in[0];
  const float* emb = (const float*)d_in[1];
  const float* Wq = (const float*)d_in[2];
  const float* bq = (const float*)d_in[3];
  const float* Wk = (const float*)d_in[4];
  const float* bk = (const float*)d_in[5];
  const float* Wv = (const float*)d_in[6];
  const float* bv = (const float*)d_in[7];
  const float* Wo = (const float*)d_in[8];
  const float* bo = (const float*)d_in[9];
  const float* ln1g = (const float*)d_in[10];
  const float* ln1b = (const float*)d_in[11];
  const float* W1 = (const float*)d_in[12];
  const float* b1 = (const float*)d_in[13];
  const float* W2 = (const float*)d_in[14];
  const float* b2 = (const float*)d_in[15];
  const float* ln2g = (const float*)d_in[16];
  const float* ln2b = (const float*)d_in[17];

  char* ws = (char*)d_ws;
  size_t off = 0;
  auto alloc = [&](size_t bytes) {
    char* p = ws + off;
    off += (bytes + 255) & ~(size_t)255;
    return p;
  };
  unsigned short* wqkv_t = (unsigned short*)alloc((size_t)NLAYER * 3072 * 1024 * 2);
  unsigned short* wo_t = (unsigned short*)alloc((size_t)NLAYER * 1024 * 1024 * 2);
  unsigned short* w1_t = (unsigned short*)alloc((size_t)NLAYER * 4096 * 1024 * 2);
  unsigned short* w2_t = (unsigned short*)alloc((size_t)NLAYER * 1024 * 4096 * 2);
  float* qkvb = (float*)alloc((size_t)NLAYER * 3072 * 4);
  float* xf = (float*)alloc((size_t)4096 * 1024 * 4);
  float* yf = (float*)alloc((size_t)4096 * 1024 * 4);
  unsigned short* xb = (unsigned short*)alloc((size_t)4096 * 1024 * 2);
  unsigned short* qkv = (unsigned short*)alloc((size_t)4096 * 3072 * 2);
  unsigned short* attn = (unsigned short*)alloc((size_t)4096 * 1024 * 2);
  unsigned short* hb = (unsigned short*)alloc((size_t)4096 * 4096 * 2);

  embed_kernel<<<dim3(4096), dim3(256), 0, stream>>>(tok, emb, xf, xb);
  dim3 tb(32, 8);
  trconv_kernel<<<dim3(32, 32, 4), tb, 0, stream>>>(Wq, wqkv_t, 1024, 1024, 1048576L, 3145728L);
  trconv_kernel<<<dim3(32, 32, 4), tb, 0, stream>>>(Wk, wqkv_t + 1048576, 1024, 1024, 1048576L, 3145728L);
  trconv_kernel<<<dim3(32, 32, 4), tb, 0, stream>>>(Wv, wqkv_t + 2097152, 1024, 1024, 1048576L, 3145728L);
  trconv_kernel<<<dim3(32, 32, 4), tb, 0, stream>>>(Wo, wo_t, 1024, 1024, 1048576L, 1048576L);
  trconv_kernel<<<dim3(128, 32, 4), tb, 0, stream>>>(W1, w1_t, 1024, 4096, 4194304L, 4194304L);
  trconv_kernel<<<dim3(32, 128, 4), tb, 0, stream>>>(W2, w2_t, 4096, 1024, 4194304L, 4194304L);
  qkvb_kernel<<<dim3(48), dim3(256), 0, stream>>>(bq, bk, bv, qkvb);

  for (int l = 0; l < NLAYER; ++l) {
    gemm_bf16<0, 0, 1><<<dim3(24, 32), dim3(256), 0, stream>>>(
        xb, wqkv_t + (size_t)l * 3145728, qkvb + l * 3072, nullptr, qkv, 4096, 3072, 1024, 1024);
    attn_kernel<<<dim3(16, 64), dim3(256), 0, stream>>>(qkv, attn);
    gemm_bf16<0, 1, 0><<<dim3(8, 32), dim3(256), 0, stream>>>(
        attn, wo_t + (size_t)l * 1048576, bo + l * 1024, yf, nullptr, 4096, 1024, 1024, 0);
    ln_kernel<<<dim3(4096), dim3(256), 0, stream>>>(
        xf, yf, ln1g + l * 1024, ln1b + l * 1024, xf, xb, nullptr);
    gemm_bf16<1, 0, 1><<<dim3(32, 32), dim3(256), 0, stream>>>(
        xb, w1_t + (size_t)l * 4194304, b1 + l * 4096, nullptr, hb, 4096, 4096, 1024, 0);
    gemm_bf16<0, 1, 0><<<dim3(8, 32), dim3(256), 0, stream>>>(
        hb, w2_t + (size_t)l * 4194304, b2 + l * 1024, yf, nullptr, 4096, 1024, 4096, 0);
    ln_kernel<<<dim3(4096), dim3(256), 0, stream>>>(
        xf, yf, ln2g + l * 1024, ln2b + l * 1024, xf, xb,
        (l == NLAYER - 1) ? (float*)d_out : nullptr);
  }
}